// Round 1
// baseline (3337.866 us; speedup 1.0000x reference)
//
#include <hip/hip_runtime.h>
#include <math.h>

// Problem constants (from reference setup_inputs)
#define B_    256
#define T_    10
#define D_    512
#define H_    1024
#define FF_   2048
#define NHEAD 16
#define HD    64          // head dim
#define M_    (B_ * T_)   // 2560 tokens
#define NL    2           // layers

__device__ inline float sigmoidf_(float x) { return 1.0f / (1.0f + expf(-x)); }

// ---------------------------------------------------------------------------
// Generic GEMM: C[M,N] = A[M,K] * W[N,K]^T + bias[N], optional ReLU.
// Both A and W are row-major with K contiguous (the "B-transposed" form that
// every matmul in this model has, since PyTorch weights are [out,in]).
// 64x64 tile, BK=16, 256 threads, 4x4 acc/thread.
// All M % 64 == 0, N % 64 == 0, K % 16 == 0 in this model -> no guards.
// ---------------------------------------------------------------------------
template<bool RELU>
__global__ __launch_bounds__(256) void gemm_bt(const float* __restrict__ A,
                                               const float* __restrict__ W,
                                               const float* __restrict__ bias,
                                               float* __restrict__ C,
                                               int M, int N, int K)
{
    // k-major LDS tiles; pad 64->68 floats: write conflicts are 2-way (free),
    // reads As[k][ty*4..+3] are 16B-aligned -> ds_read_b128.
    __shared__ float As[16][68];
    __shared__ float Ws[16][68];

    const int tx = threadIdx.x & 15;   // n-tile coord
    const int ty = threadIdx.x >> 4;   // m-tile coord
    const int m0 = blockIdx.y * 64;
    const int n0 = blockIdx.x * 64;

    // staging: each thread loads one float4 of A and one of W per k-tile
    const int r  = threadIdx.x >> 2;        // 0..63 tile row
    const int c4 = (threadIdx.x & 3) << 2;  // 0,4,8,12 k offset
    const float* Aptr = A + (size_t)(m0 + r) * K + c4;
    const float* Wptr = W + (size_t)(n0 + r) * K + c4;

    float acc[4][4] = {};

    for (int k0 = 0; k0 < K; k0 += 16) {
        const float4 a4 = *reinterpret_cast<const float4*>(Aptr + k0);
        const float4 w4 = *reinterpret_cast<const float4*>(Wptr + k0);
        As[c4 + 0][r] = a4.x; As[c4 + 1][r] = a4.y;
        As[c4 + 2][r] = a4.z; As[c4 + 3][r] = a4.w;
        Ws[c4 + 0][r] = w4.x; Ws[c4 + 1][r] = w4.y;
        Ws[c4 + 2][r] = w4.z; Ws[c4 + 3][r] = w4.w;
        __syncthreads();
#pragma unroll
        for (int k = 0; k < 16; ++k) {
            float a[4], b[4];
#pragma unroll
            for (int i = 0; i < 4; ++i) a[i] = As[k][ty * 4 + i];
#pragma unroll
            for (int j = 0; j < 4; ++j) b[j] = Ws[k][tx * 4 + j];
#pragma unroll
            for (int i = 0; i < 4; ++i)
#pragma unroll
                for (int j = 0; j < 4; ++j)
                    acc[i][j] = fmaf(a[i], b[j], acc[i][j]);
        }
        __syncthreads();
    }

#pragma unroll
    for (int i = 0; i < 4; ++i) {
        const int m = m0 + ty * 4 + i;
#pragma unroll
        for (int j = 0; j < 4; ++j) {
            const int n = n0 + tx * 4 + j;
            float v = acc[i][j] + (bias ? bias[n] : 0.0f);
            if (RELU) v = fmaxf(v, 0.0f);
            C[(size_t)m * N + n] = v;
        }
    }
}

// ---------------------------------------------------------------------------
// Causal MHA for one (batch, head): T=10, hd=64 fits entirely in LDS.
// qkv layout: [M_, 3H] rows; q at col h*64, k at 1024+h*64, v at 2048+h*64.
// Writes ctx[M_, H] (pre-out_proj context).
// ---------------------------------------------------------------------------
__global__ __launch_bounds__(256) void attn_kernel(const float* __restrict__ qkv,
                                                   float* __restrict__ ctx)
{
    const int bh = blockIdx.x;          // 0..4095
    const int b  = bh >> 4;
    const int h  = bh & 15;

    __shared__ float q[T_][HD], k[T_][HD], v[T_][HD];
    __shared__ float p[T_][T_];

    for (int idx = threadIdx.x; idx < T_ * HD; idx += 256) {
        const int t = idx >> 6, d = idx & 63;
        const float* row = qkv + (size_t)(b * T_ + t) * (3 * H_) + h * HD + d;
        q[t][d] = row[0];
        k[t][d] = row[H_];
        v[t][d] = row[2 * H_];
    }
    __syncthreads();

    if (threadIdx.x < T_ * T_) {
        const int qi = threadIdx.x / T_, ki = threadIdx.x % T_;
        float s = 0.0f;
        if (ki <= qi) {
            for (int d = 0; d < HD; ++d) s = fmaf(q[qi][d], k[ki][d], s);
            s *= 0.125f;  // 1/sqrt(64)
        }
        p[qi][ki] = s;    // masked entries overwritten to 0 in softmax phase
    }
    __syncthreads();

    if (threadIdx.x < T_) {
        const int rq = threadIdx.x;
        float mx = -1e30f;
        for (int ki = 0; ki <= rq; ++ki) mx = fmaxf(mx, p[rq][ki]);
        float sum = 0.0f;
        for (int ki = 0; ki <= rq; ++ki) { const float e = expf(p[rq][ki] - mx); p[rq][ki] = e; sum += e; }
        const float inv = 1.0f / sum;
        for (int ki = 0; ki <= rq; ++ki) p[rq][ki] *= inv;
        for (int ki = rq + 1; ki < T_; ++ki) p[rq][ki] = 0.0f;
    }
    __syncthreads();

    for (int idx = threadIdx.x; idx < T_ * HD; idx += 256) {
        const int t = idx >> 6, d = idx & 63;
        float s = 0.0f;
        for (int ki = 0; ki <= t; ++ki) s = fmaf(p[t][ki], v[ki][d], s);
        ctx[(size_t)(b * T_ + t) * H_ + h * HD + d] = s;
    }
}

// ---------------------------------------------------------------------------
// Fused residual-add + LayerNorm over H=1024: out = LN(x + res) * w + b.
// One block (256 threads) per row.
// ---------------------------------------------------------------------------
__global__ __launch_bounds__(256) void ln_kernel(const float* __restrict__ x,
                                                 const float* __restrict__ res,
                                                 const float* __restrict__ w,
                                                 const float* __restrict__ b,
                                                 float* __restrict__ out)
{
    const int row = blockIdx.x;
    const float* xr = x + (size_t)row * H_;
    const float* rr = res + (size_t)row * H_;

    float vals[4];
    float s = 0.0f, s2 = 0.0f;
#pragma unroll
    for (int i = 0; i < 4; ++i) {
        const int c = threadIdx.x + i * 256;
        const float vv = xr[c] + rr[c];
        vals[i] = vv;
        s += vv;
        s2 = fmaf(vv, vv, s2);
    }
    // wave64 reduce, then cross-wave via LDS
    for (int off = 32; off; off >>= 1) {
        s  += __shfl_down(s, off);
        s2 += __shfl_down(s2, off);
    }
    __shared__ float rs_[4], rs2_[4];
    const int wave = threadIdx.x >> 6, lane = threadIdx.x & 63;
    if (lane == 0) { rs_[wave] = s; rs2_[wave] = s2; }
    __syncthreads();
    const float st  = rs_[0] + rs_[1] + rs_[2] + rs_[3];
    const float st2 = rs2_[0] + rs2_[1] + rs2_[2] + rs2_[3];
    const float m   = st * (1.0f / 1024.0f);
    const float var = st2 * (1.0f / 1024.0f) - m * m;
    const float rsv = rsqrtf(var + 1e-5f);
#pragma unroll
    for (int i = 0; i < 4; ++i) {
        const int c = threadIdx.x + i * 256;
        out[(size_t)row * H_ + c] = (vals[i] - m) * rsv * w[c] + b[c];
    }
}

// ---------------------------------------------------------------------------
// LSTM pointwise cell for one timestep. gx = precomputed x@W_ih^T + (b_ih+b_hh)
// over all tokens [M_,4H]; ghh = h@W_hh^T for this step [B_,4H].
// Gate order (i,f,g,o). At t==T-1 writes hT/cT into d_out slices.
// ---------------------------------------------------------------------------
__global__ __launch_bounds__(256) void lstm_point(const float* __restrict__ gx,
                                                  const float* __restrict__ ghh,
                                                  float* __restrict__ hstate,
                                                  float* __restrict__ cstate,
                                                  float* __restrict__ lstm_out,
                                                  int t,
                                                  float* __restrict__ hT_out,  // base + layer*H, idx b*2H+j
                                                  float* __restrict__ cT_out)
{
    const int id = blockIdx.x * 256 + threadIdx.x;   // 0 .. B_*H_-1
    const int b  = id >> 10;
    const int j  = id & 1023;
    const float* g1 = gx + (size_t)(b * T_ + t) * (4 * H_);
    const float* g2 = ghh + (size_t)b * (4 * H_);

    const float gi = g1[j]            + g2[j];
    const float gf = g1[H_ + j]       + g2[H_ + j];
    const float gg = g1[2 * H_ + j]   + g2[2 * H_ + j];
    const float go = g1[3 * H_ + j]   + g2[3 * H_ + j];

    const float c  = sigmoidf_(gf) * cstate[id] + sigmoidf_(gi) * tanhf(gg);
    const float hh = sigmoidf_(go) * tanhf(c);
    cstate[id] = c;
    hstate[id] = hh;
    lstm_out[(size_t)(b * T_ + t) * H_ + j] = hh;
    if (hT_out) {
        hT_out[(size_t)b * (NL * H_) + j] = hh;
        cT_out[(size_t)b * (NL * H_) + j] = c;
    }
}

// Initialize LSTM states from user_vector / game_vector slices [:, layer, :]
__global__ __launch_bounds__(256) void init_states(const float* __restrict__ uvec,
                                                   const float* __restrict__ gvec,
                                                   int layer,
                                                   float* __restrict__ hstate,
                                                   float* __restrict__ cstate)
{
    const int id = blockIdx.x * 256 + threadIdx.x;
    const int b  = id >> 10;
    const int j  = id & 1023;
    hstate[id] = uvec[(size_t)(b * NL + layer) * H_ + j];
    cstate[id] = gvec[(size_t)(b * NL + layer) * H_ + j];
}

__global__ __launch_bounds__(256) void bias_sum(const float* __restrict__ a,
                                                const float* __restrict__ b,
                                                float* __restrict__ o)
{
    const int i = blockIdx.x * 256 + threadIdx.x;
    o[i] = a[i] + b[i];
}

// ---------------------------------------------------------------------------
// Head: o = o1 @ out2_w^T + out2_b (N=2), then log_softmax over the 2 classes.
// One wave per token, 4 tokens per block.
// ---------------------------------------------------------------------------
__global__ __launch_bounds__(256) void head_kernel(const float* __restrict__ o1,
                                                   const float* __restrict__ w2,
                                                   const float* __restrict__ b2,
                                                   float* __restrict__ out)
{
    const int token = blockIdx.x * 4 + (threadIdx.x >> 6);
    const int lane  = threadIdx.x & 63;
    const float* row = o1 + (size_t)token * (H_ / 2);
    float s0 = 0.0f, s1 = 0.0f;
    for (int c = lane; c < H_ / 2; c += 64) {
        const float xv = row[c];
        s0 = fmaf(xv, w2[c], s0);
        s1 = fmaf(xv, w2[H_ / 2 + c], s1);
    }
    for (int off = 32; off; off >>= 1) {
        s0 += __shfl_down(s0, off);
        s1 += __shfl_down(s1, off);
    }
    if (lane == 0) {
        const float o0 = s0 + b2[0];
        const float o1v = s1 + b2[1];
        const float mx = fmaxf(o0, o1v);
        const float lse = mx + logf(expf(o0 - mx) + expf(o1v - mx));
        out[(size_t)token * 2 + 0] = o0 - lse;
        out[(size_t)token * 2 + 1] = o1v - lse;
    }
}

// ---------------------------------------------------------------------------
extern "C" void kernel_launch(void* const* d_in, const int* in_sizes, int n_in,
                              void* d_out, int out_size, void* d_ws, size_t ws_size,
                              hipStream_t stream)
{
    const float* x         = (const float*)d_in[0];
    const float* user_vec  = (const float*)d_in[1];
    const float* game_vec  = (const float*)d_in[2];
    const float* fc_w      = (const float*)d_in[3];
    const float* fc_b      = (const float*)d_in[4];
    const float* in_proj_w = (const float*)d_in[5];
    const float* in_proj_b = (const float*)d_in[6];
    const float* out_proj_w= (const float*)d_in[7];
    const float* out_proj_b= (const float*)d_in[8];
    const float* ln1_w     = (const float*)d_in[9];
    const float* ln1_b     = (const float*)d_in[10];
    const float* ff1_w     = (const float*)d_in[11];
    const float* ff1_b     = (const float*)d_in[12];
    const float* ff2_w     = (const float*)d_in[13];
    const float* ff2_b     = (const float*)d_in[14];
    const float* ln2_w     = (const float*)d_in[15];
    const float* ln2_b     = (const float*)d_in[16];
    const float* w_ih      = (const float*)d_in[17];
    const float* w_hh      = (const float*)d_in[18];
    const float* b_ih      = (const float*)d_in[19];
    const float* b_hh      = (const float*)d_in[20];
    const float* out1_w    = (const float*)d_in[21];
    const float* out1_b    = (const float*)d_in[22];
    const float* out2_w    = (const float*)d_in[23];
    const float* out2_b    = (const float*)d_in[24];
    float* out = (float*)d_out;

    // Workspace layout (floats). Total ~26.8M floats ~= 107 MB.
    float* ws = (float*)d_ws;
    float* buf0   = ws;                 ws += (size_t)M_ * H_;        // 2.62M
    float* buf1   = ws;                 ws += (size_t)M_ * H_;        // 2.62M
    float* ctx    = ws;                 ws += (size_t)M_ * H_;        // 2.62M
    float* tmp1   = ws;                 ws += (size_t)M_ * FF_;       // 5.24M
    float* tmp2   = ws;                 ws += (size_t)M_ * H_;        // 2.62M
    float* big    = ws;                 ws += (size_t)M_ * 4 * H_;    // 10.49M
    float* hstate = ws;                 ws += (size_t)B_ * H_;
    float* cstate = ws;                 ws += (size_t)B_ * H_;
    float* bsum   = ws;                 ws += 4 * H_;

    float* gv_out = out + (size_t)M_ * 2;                       // [B, NL, H] of cT
    float* uv_out = gv_out + (size_t)B_ * NL * H_;              // [B, NL, H] of hT

    auto gemm = [&](const float* A, const float* W, const float* bias, float* C,
                    int M, int N, int K, bool relu) {
        dim3 grid(N / 64, M / 64);
        if (relu) hipLaunchKernelGGL((gemm_bt<true>),  grid, dim3(256), 0, stream, A, W, bias, C, M, N, K);
        else      hipLaunchKernelGGL((gemm_bt<false>), grid, dim3(256), 0, stream, A, W, bias, C, M, N, K);
    };

    // combined LSTM bias (b_ih + b_hh), folded into the batched input GEMM
    hipLaunchKernelGGL(bias_sum, dim3(4 * H_ / 256), dim3(256), 0, stream, b_ih, b_hh, bsum);

    // fc: h = relu(x @ fc_w^T + fc_b)   [2560,512]x[1024,512]^T
    gemm(x, fc_w, fc_b, buf0, M_, H_, D_, true);

    float* h    = buf0;
    float* lout = buf1;

    for (int layer = 0; layer < NL; ++layer) {
        // --- encoder layer (shared weights) ---
        gemm(h, in_proj_w, in_proj_b, big, M_, 3 * H_, H_, false);        // qkv
        hipLaunchKernelGGL(attn_kernel, dim3(B_ * NHEAD), dim3(256), 0, stream, big, ctx);
        gemm(ctx, out_proj_w, out_proj_b, tmp1, M_, H_, H_, false);       // attn out
        hipLaunchKernelGGL(ln_kernel, dim3(M_), dim3(256), 0, stream, h, tmp1, ln1_w, ln1_b, tmp2);
        gemm(tmp2, ff1_w, ff1_b, tmp1, M_, FF_, H_, true);                // relu(ff1)
        gemm(tmp1, ff2_w, ff2_b, ctx, M_, H_, FF_, false);                // ff2
        hipLaunchKernelGGL(ln_kernel, dim3(M_), dim3(256), 0, stream, tmp2, ctx, ln2_w, ln2_b, h); // enc -> h

        // --- LSTM ---
        gemm(h, w_ih, bsum, big, M_, 4 * H_, H_, false);                  // x-part of gates, all t
        hipLaunchKernelGGL(init_states, dim3(B_ * H_ / 256), dim3(256), 0, stream,
                           user_vec, game_vec, layer, hstate, cstate);
        for (int t = 0; t < T_; ++t) {
            gemm(hstate, w_hh, nullptr, tmp1, B_, 4 * H_, H_, false);     // h-part of gates
            const bool last = (t == T_ - 1);
            hipLaunchKernelGGL(lstm_point, dim3(B_ * H_ / 256), dim3(256), 0, stream,
                               big, tmp1, hstate, cstate, lout, t,
                               last ? (uv_out + layer * H_) : nullptr,
                               last ? (gv_out + layer * H_) : nullptr);
        }
        // next layer input = lstm output; ping-pong buffers
        float* tswap = h; h = lout; lout = tswap;
    }

    // head: o1 = relu(lstm_out @ out1_w^T + out1_b)  [2560,1024]x[512,1024]^T
    gemm(h, out1_w, out1_b, ctx, M_, H_ / 2, H_, true);
    hipLaunchKernelGGL(head_kernel, dim3(M_ / 4), dim3(256), 0, stream, ctx, out2_w, out2_b, out);
}

// Round 2
// 1103.232 us; speedup vs baseline: 3.0255x; 3.0255x over previous
//
#include <hip/hip_runtime.h>
#include <math.h>

// Problem constants
#define B_    256
#define T_    10
#define D_    512
#define H_    1024
#define FF_   2048
#define NHEAD 16
#define HD    64
#define M_    (B_ * T_)   // 2560 tokens
#define NL    2

typedef unsigned short u16;
typedef unsigned int   u32;
typedef __attribute__((ext_vector_type(8))) short bf16x8;
typedef __attribute__((ext_vector_type(4))) float f32x4;

__device__ inline float sigmoidf_(float x) { return 1.0f / (1.0f + expf(-x)); }
__device__ inline float b2f(u16 v) { return __uint_as_float(((u32)v) << 16); }
__device__ inline u16 f2b(float f) {
    u32 u = __float_as_uint(f);
    return (u16)((u + 0x7fffu + ((u >> 16) & 1u)) >> 16);
}

// ---------------------------------------------------------------------------
// f32 -> bf16 convert (RNE). n % 256 == 0 for all uses.
// ---------------------------------------------------------------------------
__global__ __launch_bounds__(256) void cvt_f2b(const float* __restrict__ a,
                                               u16* __restrict__ o, int n)
{
    const int i = blockIdx.x * 256 + threadIdx.x;
    if (i < n) o[i] = f2b(a[i]);
}

// ---------------------------------------------------------------------------
// MFMA bf16 GEMM: C[M,N] = A[M,K](bf16) * W[N,K](bf16)^T + bias, opt ReLU.
// Tile BM x BN, BK=32, 256 threads = 4 waves in 2x2; wave tile (BM/2)x(BN/2)
// of 16x16x32 mfma frags. global_load_lds width-16 staging; LDS tiles are
// [BM][32] / [BN][32] bf16 row-major (the exact lane order global_load_lds
// produces). Dual epilogue: f32 C and/or bf16 C.
// Requires M%BM==0, N%BN==0, K%32==0 (true for every GEMM in this model).
// ---------------------------------------------------------------------------
template<int BM, int BN, bool RELU, bool WF32, bool WB16>
__global__ __launch_bounds__(256) void gemm_mfma(const u16* __restrict__ A,
                                                 const u16* __restrict__ W,
                                                 const float* __restrict__ bias,
                                                 float* __restrict__ Cf,
                                                 u16* __restrict__ Cb,
                                                 int M, int N, int K)
{
    constexpr int MI = BM / 32;   // m-frags per wave
    constexpr int NJ = BN / 32;   // n-frags per wave
    __shared__ alignas(16) u16 As[BM * 32];
    __shared__ alignas(16) u16 Bs[BN * 32];

    const int wave = threadIdx.x >> 6;
    const int lane = threadIdx.x & 63;
    const int m0 = blockIdx.y * BM;
    const int n0 = blockIdx.x * BN;
    const int wm = (wave >> 1) * (BM / 2);
    const int wn = (wave & 1) * (BN / 2);
    const int lr = lane >> 2;          // staging: row within 16-row chunk
    const int lc = (lane & 3) * 8;     // staging: bf16 col offset (16B)
    const int fr = lane & 15;          // frag row/col
    const int kq = lane >> 4;          // frag k-quad

    f32x4 acc[MI][NJ] = {};

    for (int k0 = 0; k0 < K; k0 += 32) {
        // stage A: BM/16 chunks of 16 rows x 64B, round-robin over waves
#pragma unroll
        for (int cc = 0; cc < BM / 64; ++cc) {
            const int c = cc * 4 + wave;
            const u16* g = A + (size_t)(m0 + c * 16 + lr) * K + k0 + lc;
            __builtin_amdgcn_global_load_lds(
                (const __attribute__((address_space(1))) void*)g,
                (__attribute__((address_space(3))) void*)(As + c * 512), 16, 0, 0);
        }
#pragma unroll
        for (int cc = 0; cc < BN / 64; ++cc) {
            const int c = cc * 4 + wave;
            const u16* g = W + (size_t)(n0 + c * 16 + lr) * K + k0 + lc;
            __builtin_amdgcn_global_load_lds(
                (const __attribute__((address_space(1))) void*)g,
                (__attribute__((address_space(3))) void*)(Bs + c * 512), 16, 0, 0);
        }
        __syncthreads();

        bf16x8 a[MI], b[NJ];
#pragma unroll
        for (int i = 0; i < MI; ++i)
            a[i] = *(const bf16x8*)(As + (wm + i * 16 + fr) * 32 + kq * 8);
#pragma unroll
        for (int j = 0; j < NJ; ++j)
            b[j] = *(const bf16x8*)(Bs + (wn + j * 16 + fr) * 32 + kq * 8);
#pragma unroll
        for (int i = 0; i < MI; ++i)
#pragma unroll
            for (int j = 0; j < NJ; ++j)
                acc[i][j] = __builtin_amdgcn_mfma_f32_16x16x32_bf16(a[i], b[j], acc[i][j], 0, 0, 0);
        __syncthreads();
    }

    // epilogue: C/D frag layout col=lane&15, row=(lane>>4)*4+r
#pragma unroll
    for (int i = 0; i < MI; ++i) {
#pragma unroll
        for (int j = 0; j < NJ; ++j) {
            const int col = n0 + wn + j * 16 + fr;
            const float bv = bias ? bias[col] : 0.0f;
#pragma unroll
            for (int r = 0; r < 4; ++r) {
                const int row = m0 + wm + i * 16 + kq * 4 + r;
                float v = acc[i][j][r] + bv;
                if (RELU) v = fmaxf(v, 0.0f);
                if (WF32) Cf[(size_t)row * N + col] = v;
                if (WB16) Cb[(size_t)row * N + col] = f2b(v);
            }
        }
    }
}

// ---------------------------------------------------------------------------
// Causal MHA for one (batch, head), bf16 qkv in, bf16 ctx out.
// qkv layout: [M_, 3H] rows; q at col h*64, k at 1024+h*64, v at 2048+h*64.
// ---------------------------------------------------------------------------
__global__ __launch_bounds__(256) void attn_kernel(const u16* __restrict__ qkv,
                                                   u16* __restrict__ ctx)
{
    const int bh = blockIdx.x;
    const int b  = bh >> 4;
    const int h  = bh & 15;

    __shared__ float q[T_][HD], k[T_][HD], v[T_][HD];
    __shared__ float p[T_][T_];

    for (int idx = threadIdx.x; idx < T_ * HD; idx += 256) {
        const int t = idx >> 6, d = idx & 63;
        const u16* row = qkv + (size_t)(b * T_ + t) * (3 * H_) + h * HD + d;
        q[t][d] = b2f(row[0]);
        k[t][d] = b2f(row[H_]);
        v[t][d] = b2f(row[2 * H_]);
    }
    __syncthreads();

    if (threadIdx.x < T_ * T_) {
        const int qi = threadIdx.x / T_, ki = threadIdx.x % T_;
        float s = 0.0f;
        if (ki <= qi) {
            for (int d = 0; d < HD; ++d) s = fmaf(q[qi][d], k[ki][d], s);
            s *= 0.125f;
        }
        p[qi][ki] = s;
    }
    __syncthreads();

    if (threadIdx.x < T_) {
        const int rq = threadIdx.x;
        float mx = -1e30f;
        for (int ki = 0; ki <= rq; ++ki) mx = fmaxf(mx, p[rq][ki]);
        float sum = 0.0f;
        for (int ki = 0; ki <= rq; ++ki) { const float e = expf(p[rq][ki] - mx); p[rq][ki] = e; sum += e; }
        const float inv = 1.0f / sum;
        for (int ki = 0; ki <= rq; ++ki) p[rq][ki] *= inv;
        for (int ki = rq + 1; ki < T_; ++ki) p[rq][ki] = 0.0f;
    }
    __syncthreads();

    for (int idx = threadIdx.x; idx < T_ * HD; idx += 256) {
        const int t = idx >> 6, d = idx & 63;
        float s = 0.0f;
        for (int ki = 0; ki <= t; ++ki) s = fmaf(p[t][ki], v[ki][d], s);
        ctx[(size_t)(b * T_ + t) * H_ + h * HD + d] = f2b(s);
    }
}

// ---------------------------------------------------------------------------
// Fused residual-add + LayerNorm: out = LN(x + res) * w + b.
// Writes f32 and/or bf16 (null = skip). One block per row.
// ---------------------------------------------------------------------------
__global__ __launch_bounds__(256) void ln_kernel(const float* __restrict__ x,
                                                 const float* __restrict__ res,
                                                 const float* __restrict__ w,
                                                 const float* __restrict__ b,
                                                 float* __restrict__ outf,
                                                 u16* __restrict__ outb)
{
    const int row = blockIdx.x;
    const float* xr = x + (size_t)row * H_;
    const float* rr = res + (size_t)row * H_;

    float vals[4];
    float s = 0.0f, s2 = 0.0f;
#pragma unroll
    for (int i = 0; i < 4; ++i) {
        const int c = threadIdx.x + i * 256;
        const float vv = xr[c] + rr[c];
        vals[i] = vv;
        s += vv;
        s2 = fmaf(vv, vv, s2);
    }
    for (int off = 32; off; off >>= 1) {
        s  += __shfl_down(s, off);
        s2 += __shfl_down(s2, off);
    }
    __shared__ float rs_[4], rs2_[4];
    const int wave = threadIdx.x >> 6, lane = threadIdx.x & 63;
    if (lane == 0) { rs_[wave] = s; rs2_[wave] = s2; }
    __syncthreads();
    const float st  = rs_[0] + rs_[1] + rs_[2] + rs_[3];
    const float st2 = rs2_[0] + rs2_[1] + rs2_[2] + rs2_[3];
    const float m   = st * (1.0f / 1024.0f);
    const float var = st2 * (1.0f / 1024.0f) - m * m;
    const float rsv = rsqrtf(var + 1e-5f);
#pragma unroll
    for (int i = 0; i < 4; ++i) {
        const int c = threadIdx.x + i * 256;
        const float v = (vals[i] - m) * rsv * w[c] + b[c];
        if (outf) outf[(size_t)row * H_ + c] = v;
        if (outb) outb[(size_t)row * H_ + c] = f2b(v);
    }
}

// ---------------------------------------------------------------------------
// LSTM pointwise cell. gx bf16 [M_,4H] (x@W_ih^T + b_ih + b_hh), ghh f32
// [B_,4H]. Gate order (i,f,g,o). Writes bf16 h-state (recurrent GEMM input),
// f32 c-state, lstm_out in f32+bf16; at t==T-1 also hT/cT into d_out slices.
// ---------------------------------------------------------------------------
__global__ __launch_bounds__(256) void lstm_point(const u16* __restrict__ gx,
                                                  const float* __restrict__ ghh,
                                                  u16* __restrict__ hstate_b,
                                                  float* __restrict__ cstate,
                                                  float* __restrict__ lout_f,
                                                  u16* __restrict__ lout_b,
                                                  int t,
                                                  float* __restrict__ hT_out,
                                                  float* __restrict__ cT_out)
{
    const int id = blockIdx.x * 256 + threadIdx.x;   // 0 .. B_*H_-1
    const int b  = id >> 10;
    const int j  = id & 1023;
    const u16*   g1 = gx + (size_t)(b * T_ + t) * (4 * H_);
    const float* g2 = ghh + (size_t)b * (4 * H_);

    const float gi = b2f(g1[j])           + g2[j];
    const float gf = b2f(g1[H_ + j])      + g2[H_ + j];
    const float gg = b2f(g1[2 * H_ + j])  + g2[2 * H_ + j];
    const float go = b2f(g1[3 * H_ + j])  + g2[3 * H_ + j];

    const float c  = sigmoidf_(gf) * cstate[id] + sigmoidf_(gi) * tanhf(gg);
    const float hh = sigmoidf_(go) * tanhf(c);
    cstate[id] = c;
    hstate_b[id] = f2b(hh);
    lout_f[(size_t)(b * T_ + t) * H_ + j] = hh;
    lout_b[(size_t)(b * T_ + t) * H_ + j] = f2b(hh);
    if (hT_out) {
        hT_out[(size_t)b * (NL * H_) + j] = hh;
        cT_out[(size_t)b * (NL * H_) + j] = c;
    }
}

__global__ __launch_bounds__(256) void init_states(const float* __restrict__ uvec,
                                                   const float* __restrict__ gvec,
                                                   int layer,
                                                   u16* __restrict__ hstate_b,
                                                   float* __restrict__ cstate)
{
    const int id = blockIdx.x * 256 + threadIdx.x;
    const int b  = id >> 10;
    const int j  = id & 1023;
    hstate_b[id] = f2b(uvec[(size_t)(b * NL + layer) * H_ + j]);
    cstate[id]   = gvec[(size_t)(b * NL + layer) * H_ + j];
}

__global__ __launch_bounds__(256) void bias_sum(const float* __restrict__ a,
                                                const float* __restrict__ b,
                                                float* __restrict__ o)
{
    const int i = blockIdx.x * 256 + threadIdx.x;
    o[i] = a[i] + b[i];
}

// ---------------------------------------------------------------------------
// Head: o = o1 @ out2_w^T + out2_b (N=2) + log_softmax. One wave per token.
// ---------------------------------------------------------------------------
__global__ __launch_bounds__(256) void head_kernel(const float* __restrict__ o1,
                                                   const float* __restrict__ w2,
                                                   const float* __restrict__ b2,
                                                   float* __restrict__ out)
{
    const int token = blockIdx.x * 4 + (threadIdx.x >> 6);
    const int lane  = threadIdx.x & 63;
    const float* row = o1 + (size_t)token * (H_ / 2);
    float s0 = 0.0f, s1 = 0.0f;
    for (int c = lane; c < H_ / 2; c += 64) {
        const float xv = row[c];
        s0 = fmaf(xv, w2[c], s0);
        s1 = fmaf(xv, w2[H_ / 2 + c], s1);
    }
    for (int off = 32; off; off >>= 1) {
        s0 += __shfl_down(s0, off);
        s1 += __shfl_down(s1, off);
    }
    if (lane == 0) {
        const float o0 = s0 + b2[0];
        const float o1v = s1 + b2[1];
        const float mx = fmaxf(o0, o1v);
        const float lse = mx + logf(expf(o0 - mx) + expf(o1v - mx));
        out[(size_t)token * 2 + 0] = o0 - lse;
        out[(size_t)token * 2 + 1] = o1v - lse;
    }
}

// ---------------------------------------------------------------------------
extern "C" void kernel_launch(void* const* d_in, const int* in_sizes, int n_in,
                              void* d_out, int out_size, void* d_ws, size_t ws_size,
                              hipStream_t stream)
{
    const float* x         = (const float*)d_in[0];
    const float* user_vec  = (const float*)d_in[1];
    const float* game_vec  = (const float*)d_in[2];
    const float* fc_w      = (const float*)d_in[3];
    const float* fc_b      = (const float*)d_in[4];
    const float* in_proj_w = (const float*)d_in[5];
    const float* in_proj_b = (const float*)d_in[6];
    const float* out_proj_w= (const float*)d_in[7];
    const float* out_proj_b= (const float*)d_in[8];
    const float* ln1_w     = (const float*)d_in[9];
    const float* ln1_b     = (const float*)d_in[10];
    const float* ff1_w     = (const float*)d_in[11];
    const float* ff1_b     = (const float*)d_in[12];
    const float* ff2_w     = (const float*)d_in[13];
    const float* ff2_b     = (const float*)d_in[14];
    const float* ln2_w     = (const float*)d_in[15];
    const float* ln2_b     = (const float*)d_in[16];
    const float* w_ih      = (const float*)d_in[17];
    const float* w_hh      = (const float*)d_in[18];
    const float* b_ih      = (const float*)d_in[19];
    const float* b_hh      = (const float*)d_in[20];
    const float* out1_w    = (const float*)d_in[21];
    const float* out1_b    = (const float*)d_in[22];
    const float* out2_w    = (const float*)d_in[23];
    const float* out2_b    = (const float*)d_in[24];
    float* out = (float*)d_out;

    // ---- byte arena (lifetime-based reuse), total ~89.7 MB ----
    char* base = (char*)d_ws;
    u16* wb = (u16*)base;                         // 17.83M bf16 weights
    u16* fc_wb   = wb;
    u16* inp_wb  = wb + 524288;
    u16* outp_wb = wb + 3670016;
    u16* ff1_wb  = wb + 4718592;
    u16* ff2_wb  = wb + 6815744;
    u16* wih_b   = wb + 8912896;
    u16* whh_b   = wb + 13107200;
    u16* out1_wb = wb + 17301504;
    char* A1 = base + 35651584;   // 21.0 MB: qkv_b | tmp1+tmp2 f32 | gx_b | o1
    char* S1 = A1 + 20971520;     // 10.5 MB: x_b | ff1_b | ghh f32
    char* S2 = S1 + 10485760;     //  5.2 MB: ctx_b | ln1_b | enc_b
    u16*  hb = (u16*)(S2 + 5242880);              // h bf16 [M,H]
    float* buf0 = (float*)((char*)hb + 5242880);  // h f32 [M,H]
    float* cstate = (float*)((char*)buf0 + 10485760);
    u16*  hstate_b = (u16*)((char*)cstate + 1048576);
    float* bsum = (float*)((char*)hstate_b + 524288);

    u16*   qkv_b = (u16*)A1;
    float* tmp1  = (float*)A1;
    float* tmp2  = (float*)(A1 + 10485760);
    u16*   gx_b  = (u16*)A1;
    float* o1    = (float*)A1;
    u16*   x_b   = (u16*)S1;
    u16*   ff1b  = (u16*)S1;
    float* ghh   = (float*)S1;
    u16*   ctx_b = (u16*)S2;
    u16*   ln1b  = (u16*)S2;
    u16*   enc_b = (u16*)S2;

    float* gv_out = out + (size_t)M_ * 2;            // cT [B,NL,H]
    float* uv_out = gv_out + (size_t)B_ * NL * H_;   // hT [B,NL,H]

    auto cvt = [&](const float* src, u16* dst, int n) {
        hipLaunchKernelGGL(cvt_f2b, dim3(n / 256), dim3(256), 0, stream, src, dst, n);
    };

    hipLaunchKernelGGL(bias_sum, dim3(4 * H_ / 256), dim3(256), 0, stream, b_ih, b_hh, bsum);

    // convert input + weights to bf16
    cvt(x, x_b, M_ * D_);
    cvt(fc_w, fc_wb, H_ * D_);
    cvt(in_proj_w, inp_wb, 3 * H_ * H_);
    cvt(out_proj_w, outp_wb, H_ * H_);
    cvt(ff1_w, ff1_wb, FF_ * H_);
    cvt(ff2_w, ff2_wb, H_ * FF_);
    cvt(w_ih, wih_b, 4 * H_ * H_);
    cvt(w_hh, whh_b, 4 * H_ * H_);
    cvt(out1_w, out1_wb, (H_ / 2) * H_);

    // fc: h = relu(x @ fc_w^T + fc_b) -> f32 + bf16
    hipLaunchKernelGGL((gemm_mfma<128, 128, true, true, true>),
                       dim3(H_ / 128, M_ / 128), dim3(256), 0, stream,
                       x_b, fc_wb, fc_b, buf0, hb, M_, H_, D_);

    for (int layer = 0; layer < NL; ++layer) {
        // qkv (bf16 only)
        hipLaunchKernelGGL((gemm_mfma<128, 128, false, false, true>),
                           dim3(3 * H_ / 128, M_ / 128), dim3(256), 0, stream,
                           hb, inp_wb, in_proj_b, (float*)nullptr, qkv_b, M_, 3 * H_, H_);
        hipLaunchKernelGGL(attn_kernel, dim3(B_ * NHEAD), dim3(256), 0, stream, qkv_b, ctx_b);
        // attn out-proj (f32 only)
        hipLaunchKernelGGL((gemm_mfma<128, 128, false, true, false>),
                           dim3(H_ / 128, M_ / 128), dim3(256), 0, stream,
                           ctx_b, outp_wb, out_proj_b, tmp1, (u16*)nullptr, M_, H_, H_);
        hipLaunchKernelGGL(ln_kernel, dim3(M_), dim3(256), 0, stream,
                           buf0, tmp1, ln1_w, ln1_b, tmp2, ln1b);
        // ff1 relu (bf16 only)
        hipLaunchKernelGGL((gemm_mfma<128, 128, true, false, true>),
                           dim3(FF_ / 128, M_ / 128), dim3(256), 0, stream,
                           ln1b, ff1_wb, ff1_b, (float*)nullptr, ff1b, M_, FF_, H_);
        // ff2 (f32 only)
        hipLaunchKernelGGL((gemm_mfma<128, 128, false, true, false>),
                           dim3(H_ / 128, M_ / 128), dim3(256), 0, stream,
                           ff1b, ff2_wb, ff2_b, tmp1, (u16*)nullptr, M_, H_, FF_);
        hipLaunchKernelGGL(ln_kernel, dim3(M_), dim3(256), 0, stream,
                           tmp2, tmp1, ln2_w, ln2_b, (float*)nullptr, enc_b);
        // LSTM input gates for all t (bf16 only)
        hipLaunchKernelGGL((gemm_mfma<128, 128, false, false, true>),
                           dim3(4 * H_ / 128, M_ / 128), dim3(256), 0, stream,
                           enc_b, wih_b, bsum, (float*)nullptr, gx_b, M_, 4 * H_, H_);
        hipLaunchKernelGGL(init_states, dim3(B_ * H_ / 256), dim3(256), 0, stream,
                           user_vec, game_vec, layer, hstate_b, cstate);
        for (int t = 0; t < T_; ++t) {
            hipLaunchKernelGGL((gemm_mfma<64, 128, false, true, false>),
                               dim3(4 * H_ / 128, B_ / 64), dim3(256), 0, stream,
                               hstate_b, whh_b, (const float*)nullptr, ghh, (u16*)nullptr,
                               B_, 4 * H_, H_);
            const bool last = (t == T_ - 1);
            hipLaunchKernelGGL(lstm_point, dim3(B_ * H_ / 256), dim3(256), 0, stream,
                               gx_b, ghh, hstate_b, cstate, buf0, hb, t,
                               last ? (uv_out + layer * H_) : nullptr,
                               last ? (gv_out + layer * H_) : nullptr);
        }
    }

    // head: o1 = relu(lstm_out @ out1_w^T + out1_b), then 2-class log_softmax
    hipLaunchKernelGGL((gemm_mfma<128, 64, true, true, false>),
                       dim3((H_ / 2) / 64, M_ / 128), dim3(256), 0, stream,
                       hb, out1_wb, out1_b, o1, (u16*)nullptr, M_, H_ / 2, H_);
    hipLaunchKernelGGL(head_kernel, dim3(M_ / 4), dim3(256), 0, stream, o1, out2_w, out2_b, out);
}

// Round 3
// 898.041 us; speedup vs baseline: 3.7168x; 1.2285x over previous
//
#include <hip/hip_runtime.h>
#include <math.h>

// Problem constants
#define B_    256
#define T_    10
#define D_    512
#define H_    1024
#define FF_   2048
#define NHEAD 16
#define HD    64
#define M_    (B_ * T_)   // 2560 tokens
#define NL    2

typedef unsigned short u16;
typedef unsigned int   u32;
typedef __attribute__((ext_vector_type(8))) short bf16x8;
typedef __attribute__((ext_vector_type(4))) float f32x4;

__device__ inline float sigmoidf_(float x) { return 1.0f / (1.0f + expf(-x)); }
__device__ inline float b2f(u16 v) { return __uint_as_float(((u32)v) << 16); }
__device__ inline u16 f2b(float f) {
    u32 u = __float_as_uint(f);
    return (u16)((u + 0x7fffu + ((u >> 16) & 1u)) >> 16);
}

// ---------------------------------------------------------------------------
// f32 -> bf16 convert (RNE) for the input x.
// ---------------------------------------------------------------------------
__global__ __launch_bounds__(256) void cvt_f2b(const float* __restrict__ a,
                                               u16* __restrict__ o, int n)
{
    const int i = blockIdx.x * 256 + threadIdx.x;
    if (i < n) o[i] = f2b(a[i]);
}

// All 8 weight matrices -> one contiguous bf16 arena (offsets are constexpr).
__global__ __launch_bounds__(256) void cvt_weights(
    const float* __restrict__ fcw, const float* __restrict__ inp,
    const float* __restrict__ outp, const float* __restrict__ f1,
    const float* __restrict__ f2, const float* __restrict__ wih,
    const float* __restrict__ whh, const float* __restrict__ o1w,
    u16* __restrict__ wb)
{
    const int e = blockIdx.x * 256 + threadIdx.x;
    const float* src; int off;
    if      (e <   524288) { src = fcw;  off = 0; }
    else if (e <  3670016) { src = inp;  off = 524288; }
    else if (e <  4718592) { src = outp; off = 3670016; }
    else if (e <  6815744) { src = f1;   off = 4718592; }
    else if (e <  8912896) { src = f2;   off = 6815744; }
    else if (e < 13107200) { src = wih;  off = 8912896; }
    else if (e < 17301504) { src = whh;  off = 13107200; }
    else                   { src = o1w;  off = 17301504; }
    wb[e] = f2b(src[e - off]);
}

// ---------------------------------------------------------------------------
// MFMA bf16 GEMM v2: C[M,N] = A[M,K](bf16) * W[N,K](bf16)^T + bias, opt ReLU.
// BK=64 (two 32-k sub-tiles per barrier pair), 256 threads = 4 waves in 2x2.
// XCD-aware swizzle: contiguous lid range per XCD (id%8 heuristic), 4-m-tile
// bands within -> per-XCD L2 working set ~3.5 MB.
// Requires M%BM==0, N%BN==0, K%64==0 (true for every GEMM here).
// ---------------------------------------------------------------------------
template<int BM, int BN, bool RELU, bool WF32, bool WB16>
__global__ __launch_bounds__(256) void gemm_mfma(const u16* __restrict__ A,
                                                 const u16* __restrict__ W,
                                                 const float* __restrict__ bias,
                                                 float* __restrict__ Cf,
                                                 u16* __restrict__ Cb,
                                                 int M, int N, int K)
{
    constexpr int MI = BM / 32;
    constexpr int NJ = BN / 32;
    __shared__ alignas(16) u16 As[2 * BM * 32];
    __shared__ alignas(16) u16 Bs[2 * BN * 32];

    int bx, by;
    {
        const int gx = gridDim.x, gy = gridDim.y;
        const int total = gx * gy;
        const int id = blockIdx.y * gx + blockIdx.x;
        if (((total & 7) == 0) && ((gy & 3) == 0)) {
            const int per = total >> 3;
            const int lid = (id & 7) * per + (id >> 3);  // XCD-contiguous
            const int band = gx << 2;                    // 4 m-tiles x all n
            const int g = lid / band;
            const int r = lid - g * band;
            by = (g << 2) + (r & 3);
            bx = r >> 2;
        } else { bx = blockIdx.x; by = blockIdx.y; }
    }

    const int wave = threadIdx.x >> 6;
    const int lane = threadIdx.x & 63;
    const int m0 = by * BM;
    const int n0 = bx * BN;
    const int wm = (wave >> 1) * (BM / 2);
    const int wn = (wave & 1) * (BN / 2);
    const int lr = lane >> 2;          // staging row within 16-row chunk
    const int lc = (lane & 3) * 8;     // staging bf16 col offset (16 B)
    const int fr = lane & 15;
    const int kq = lane >> 4;

    f32x4 acc[MI][NJ] = {};

    for (int k0 = 0; k0 < K; k0 += 64) {
#pragma unroll
        for (int cc = 0; cc < BM / 64; ++cc) {
            const int c = cc * 4 + wave;
            const u16* g = A + (size_t)(m0 + c * 16 + lr) * K + k0 + lc;
#pragma unroll
            for (int kk = 0; kk < 2; ++kk)
                __builtin_amdgcn_global_load_lds(
                    (const __attribute__((address_space(1))) void*)(g + kk * 32),
                    (__attribute__((address_space(3))) void*)(As + kk * BM * 32 + c * 512), 16, 0, 0);
        }
#pragma unroll
        for (int cc = 0; cc < BN / 64; ++cc) {
            const int c = cc * 4 + wave;
            const u16* g = W + (size_t)(n0 + c * 16 + lr) * K + k0 + lc;
#pragma unroll
            for (int kk = 0; kk < 2; ++kk)
                __builtin_amdgcn_global_load_lds(
                    (const __attribute__((address_space(1))) void*)(g + kk * 32),
                    (__attribute__((address_space(3))) void*)(Bs + kk * BN * 32 + c * 512), 16, 0, 0);
        }
        __syncthreads();

#pragma unroll
        for (int kk = 0; kk < 2; ++kk) {
            bf16x8 a[MI], b[NJ];
#pragma unroll
            for (int i = 0; i < MI; ++i)
                a[i] = *(const bf16x8*)(As + kk * BM * 32 + (wm + i * 16 + fr) * 32 + kq * 8);
#pragma unroll
            for (int j = 0; j < NJ; ++j)
                b[j] = *(const bf16x8*)(Bs + kk * BN * 32 + (wn + j * 16 + fr) * 32 + kq * 8);
#pragma unroll
            for (int i = 0; i < MI; ++i)
#pragma unroll
                for (int j = 0; j < NJ; ++j)
                    acc[i][j] = __builtin_amdgcn_mfma_f32_16x16x32_bf16(a[i], b[j], acc[i][j], 0, 0, 0);
        }
        __syncthreads();
    }

#pragma unroll
    for (int i = 0; i < MI; ++i) {
#pragma unroll
        for (int j = 0; j < NJ; ++j) {
            const int col = n0 + wn + j * 16 + fr;
            const float bv = bias ? bias[col] : 0.0f;
#pragma unroll
            for (int r = 0; r < 4; ++r) {
                const int row = m0 + wm + i * 16 + kq * 4 + r;
                float v = acc[i][j][r] + bv;
                if (RELU) v = fmaxf(v, 0.0f);
                if (WF32) Cf[(size_t)row * N + col] = v;
                if (WB16) Cb[(size_t)row * N + col] = f2b(v);
            }
        }
    }
}

// ---------------------------------------------------------------------------
// Fused LSTM timestep: ghh = h_t @ W_hh^T (MFMA, BK=128), then the pointwise
// cell, all in one kernel. Block = 64 b x 32 j (x all 4 gates -> 128 W rows).
// Grid (32, 4) = 128 blocks. gx (bf16) already contains x@W_ih^T + b_ih+b_hh.
// h ping-pongs between h_in / h_out buffers (intra-launch race avoidance).
// ---------------------------------------------------------------------------
__global__ __launch_bounds__(256) void lstm_step(const u16* __restrict__ h_in,
                                                 const u16* __restrict__ Whh,
                                                 const u16* __restrict__ gx,
                                                 float* __restrict__ cstate,
                                                 u16* __restrict__ h_out,
                                                 float* __restrict__ lout_f,
                                                 u16* __restrict__ lout_b,
                                                 int t,
                                                 float* __restrict__ hT_out,
                                                 float* __restrict__ cT_out)
{
    __shared__ alignas(16) char smem[49152];          // 48 KB
    u16* As = (u16*)smem;                             // [4][64][32]  16 KB
    u16* Bs = (u16*)(smem + 16384);                   // [4][128][32] 32 KB
    float* ghs = (float*)smem;                        // [64][128] f32, aliases

    const int j0 = blockIdx.x * 32;
    const int b0 = blockIdx.y * 64;
    const int wave = threadIdx.x >> 6;
    const int lane = threadIdx.x & 63;
    const int wm = (wave >> 1) * 32;
    const int wn = (wave & 1) * 64;
    const int lr = lane >> 2;
    const int lc = (lane & 3) * 8;
    const int fr = lane & 15;
    const int kq = lane >> 4;

    f32x4 acc[2][4] = {};

    for (int k0 = 0; k0 < 1024; k0 += 128) {
        // A: 4 chunks of 16 rows, one per wave; 4 kk sub-tiles
        {
            const int c = wave;
            const u16* g = h_in + (size_t)(b0 + c * 16 + lr) * H_ + k0 + lc;
#pragma unroll
            for (int kk = 0; kk < 4; ++kk)
                __builtin_amdgcn_global_load_lds(
                    (const __attribute__((address_space(1))) void*)(g + kk * 32),
                    (__attribute__((address_space(3))) void*)(As + kk * 2048 + c * 512), 16, 0, 0);
        }
        // W: 8 chunks; local row r -> gate g=r>>5, jj=r&31 -> global row g*1024+j0+jj
#pragma unroll
        for (int cc = 0; cc < 2; ++cc) {
            const int c = cc * 4 + wave;
            const int grow = (c >> 1) * H_ + j0 + (c & 1) * 16 + lr;
            const u16* g = Whh + (size_t)grow * H_ + k0 + lc;
#pragma unroll
            for (int kk = 0; kk < 4; ++kk)
                __builtin_amdgcn_global_load_lds(
                    (const __attribute__((address_space(1))) void*)(g + kk * 32),
                    (__attribute__((address_space(3))) void*)(Bs + kk * 4096 + c * 512), 16, 0, 0);
        }
        __syncthreads();

#pragma unroll
        for (int kk = 0; kk < 4; ++kk) {
            bf16x8 a[2], b[4];
#pragma unroll
            for (int i = 0; i < 2; ++i)
                a[i] = *(const bf16x8*)(As + kk * 2048 + (wm + i * 16 + fr) * 32 + kq * 8);
#pragma unroll
            for (int j = 0; j < 4; ++j)
                b[j] = *(const bf16x8*)(Bs + kk * 4096 + (wn + j * 16 + fr) * 32 + kq * 8);
#pragma unroll
            for (int i = 0; i < 2; ++i)
#pragma unroll
                for (int j = 0; j < 4; ++j)
                    acc[i][j] = __builtin_amdgcn_mfma_f32_16x16x32_bf16(a[i], b[j], acc[i][j], 0, 0, 0);
        }
        __syncthreads();
    }

    // dump ghh tile to LDS (aliases the staging tiles, which are now dead)
#pragma unroll
    for (int i = 0; i < 2; ++i)
#pragma unroll
        for (int j = 0; j < 4; ++j) {
            const int col = wn + j * 16 + fr;
#pragma unroll
            for (int r = 0; r < 4; ++r) {
                const int row = wm + i * 16 + kq * 4 + r;
                ghs[row * 128 + col] = acc[i][j][r];
            }
        }
    __syncthreads();

    // pointwise cell: 2048 cells (64 b x 32 j), 8 per thread
#pragma unroll
    for (int s = 0; s < 8; ++s) {
        const int cell = threadIdx.x + s * 256;
        const int bl = cell >> 5, jj = cell & 31;
        const int b = b0 + bl, j = j0 + jj;
        const u16* g1 = gx + (size_t)(b * T_ + t) * (4 * H_) + j;
        const float gi = b2f(g1[0])        + ghs[bl * 128 +  0 + jj];
        const float gf = b2f(g1[H_])       + ghs[bl * 128 + 32 + jj];
        const float gg = b2f(g1[2 * H_])   + ghs[bl * 128 + 64 + jj];
        const float go = b2f(g1[3 * H_])   + ghs[bl * 128 + 96 + jj];
        const int sid = b * H_ + j;
        const float c  = sigmoidf_(gf) * cstate[sid] + sigmoidf_(gi) * tanhf(gg);
        const float hh = sigmoidf_(go) * tanhf(c);
        cstate[sid] = c;
        h_out[sid]  = f2b(hh);
        lout_f[(size_t)(b * T_ + t) * H_ + j] = hh;
        lout_b[(size_t)(b * T_ + t) * H_ + j] = f2b(hh);
        if (hT_out) {
            hT_out[(size_t)b * (NL * H_) + j] = hh;
            cT_out[(size_t)b * (NL * H_) + j] = c;
        }
    }
}

// ---------------------------------------------------------------------------
// Causal MHA for one (batch, head), bf16 qkv in, bf16 ctx out.
// ---------------------------------------------------------------------------
__global__ __launch_bounds__(256) void attn_kernel(const u16* __restrict__ qkv,
                                                   u16* __restrict__ ctx)
{
    const int bh = blockIdx.x;
    const int b  = bh >> 4;
    const int h  = bh & 15;

    __shared__ float q[T_][HD], k[T_][HD], v[T_][HD];
    __shared__ float p[T_][T_];

    for (int idx = threadIdx.x; idx < T_ * HD; idx += 256) {
        const int t = idx >> 6, d = idx & 63;
        const u16* row = qkv + (size_t)(b * T_ + t) * (3 * H_) + h * HD + d;
        q[t][d] = b2f(row[0]);
        k[t][d] = b2f(row[H_]);
        v[t][d] = b2f(row[2 * H_]);
    }
    __syncthreads();

    if (threadIdx.x < T_ * T_) {
        const int qi = threadIdx.x / T_, ki = threadIdx.x % T_;
        float s = 0.0f;
        if (ki <= qi) {
            for (int d = 0; d < HD; ++d) s = fmaf(q[qi][d], k[ki][d], s);
            s *= 0.125f;
        }
        p[qi][ki] = s;
    }
    __syncthreads();

    if (threadIdx.x < T_) {
        const int rq = threadIdx.x;
        float mx = -1e30f;
        for (int ki = 0; ki <= rq; ++ki) mx = fmaxf(mx, p[rq][ki]);
        float sum = 0.0f;
        for (int ki = 0; ki <= rq; ++ki) { const float e = expf(p[rq][ki] - mx); p[rq][ki] = e; sum += e; }
        const float inv = 1.0f / sum;
        for (int ki = 0; ki <= rq; ++ki) p[rq][ki] *= inv;
        for (int ki = rq + 1; ki < T_; ++ki) p[rq][ki] = 0.0f;
    }
    __syncthreads();

    for (int idx = threadIdx.x; idx < T_ * HD; idx += 256) {
        const int t = idx >> 6, d = idx & 63;
        float s = 0.0f;
        for (int ki = 0; ki <= t; ++ki) s = fmaf(p[t][ki], v[ki][d], s);
        ctx[(size_t)(b * T_ + t) * H_ + h * HD + d] = f2b(s);
    }
}

// ---------------------------------------------------------------------------
// Fused residual-add + LayerNorm. Writes f32 and/or bf16 (null = skip).
// ---------------------------------------------------------------------------
__global__ __launch_bounds__(256) void ln_kernel(const float* __restrict__ x,
                                                 const float* __restrict__ res,
                                                 const float* __restrict__ w,
                                                 const float* __restrict__ b,
                                                 float* __restrict__ outf,
                                                 u16* __restrict__ outb)
{
    const int row = blockIdx.x;
    const float* xr = x + (size_t)row * H_;
    const float* rr = res + (size_t)row * H_;

    float vals[4];
    float s = 0.0f, s2 = 0.0f;
#pragma unroll
    for (int i = 0; i < 4; ++i) {
        const int c = threadIdx.x + i * 256;
        const float vv = xr[c] + rr[c];
        vals[i] = vv;
        s += vv;
        s2 = fmaf(vv, vv, s2);
    }
    for (int off = 32; off; off >>= 1) {
        s  += __shfl_down(s, off);
        s2 += __shfl_down(s2, off);
    }
    __shared__ float rs_[4], rs2_[4];
    const int wave = threadIdx.x >> 6, lane = threadIdx.x & 63;
    if (lane == 0) { rs_[wave] = s; rs2_[wave] = s2; }
    __syncthreads();
    const float st  = rs_[0] + rs_[1] + rs_[2] + rs_[3];
    const float st2 = rs2_[0] + rs2_[1] + rs2_[2] + rs2_[3];
    const float m   = st * (1.0f / 1024.0f);
    const float var = st2 * (1.0f / 1024.0f) - m * m;
    const float rsv = rsqrtf(var + 1e-5f);
#pragma unroll
    for (int i = 0; i < 4; ++i) {
        const int c = threadIdx.x + i * 256;
        const float v = (vals[i] - m) * rsv * w[c] + b[c];
        if (outf) outf[(size_t)row * H_ + c] = v;
        if (outb) outb[(size_t)row * H_ + c] = f2b(v);
    }
}

__global__ __launch_bounds__(256) void init_states(const float* __restrict__ uvec,
                                                   const float* __restrict__ gvec,
                                                   int layer,
                                                   u16* __restrict__ hstate_b,
                                                   float* __restrict__ cstate)
{
    const int id = blockIdx.x * 256 + threadIdx.x;
    const int b  = id >> 10;
    const int j  = id & 1023;
    hstate_b[id] = f2b(uvec[(size_t)(b * NL + layer) * H_ + j]);
    cstate[id]   = gvec[(size_t)(b * NL + layer) * H_ + j];
}

__global__ __launch_bounds__(256) void bias_sum(const float* __restrict__ a,
                                                const float* __restrict__ b,
                                                float* __restrict__ o)
{
    const int i = blockIdx.x * 256 + threadIdx.x;
    o[i] = a[i] + b[i];
}

// ---------------------------------------------------------------------------
// Head: o = o1 @ out2_w^T + out2_b (N=2) + log_softmax. One wave per token.
// ---------------------------------------------------------------------------
__global__ __launch_bounds__(256) void head_kernel(const float* __restrict__ o1,
                                                   const float* __restrict__ w2,
                                                   const float* __restrict__ b2,
                                                   float* __restrict__ out)
{
    const int token = blockIdx.x * 4 + (threadIdx.x >> 6);
    const int lane  = threadIdx.x & 63;
    const float* row = o1 + (size_t)token * (H_ / 2);
    float s0 = 0.0f, s1 = 0.0f;
    for (int c = lane; c < H_ / 2; c += 64) {
        const float xv = row[c];
        s0 = fmaf(xv, w2[c], s0);
        s1 = fmaf(xv, w2[H_ / 2 + c], s1);
    }
    for (int off = 32; off; off >>= 1) {
        s0 += __shfl_down(s0, off);
        s1 += __shfl_down(s1, off);
    }
    if (lane == 0) {
        const float o0 = s0 + b2[0];
        const float o1v = s1 + b2[1];
        const float mx = fmaxf(o0, o1v);
        const float lse = mx + logf(expf(o0 - mx) + expf(o1v - mx));
        out[(size_t)token * 2 + 0] = o0 - lse;
        out[(size_t)token * 2 + 1] = o1v - lse;
    }
}

// ---------------------------------------------------------------------------
extern "C" void kernel_launch(void* const* d_in, const int* in_sizes, int n_in,
                              void* d_out, int out_size, void* d_ws, size_t ws_size,
                              hipStream_t stream)
{
    const float* x         = (const float*)d_in[0];
    const float* user_vec  = (const float*)d_in[1];
    const float* game_vec  = (const float*)d_in[2];
    const float* fc_w      = (const float*)d_in[3];
    const float* fc_b      = (const float*)d_in[4];
    const float* in_proj_w = (const float*)d_in[5];
    const float* in_proj_b = (const float*)d_in[6];
    const float* out_proj_w= (const float*)d_in[7];
    const float* out_proj_b= (const float*)d_in[8];
    const float* ln1_w     = (const float*)d_in[9];
    const float* ln1_b     = (const float*)d_in[10];
    const float* ff1_w     = (const float*)d_in[11];
    const float* ff1_b     = (const float*)d_in[12];
    const float* ff2_w     = (const float*)d_in[13];
    const float* ff2_b     = (const float*)d_in[14];
    const float* ln2_w     = (const float*)d_in[15];
    const float* ln2_b     = (const float*)d_in[16];
    const float* w_ih      = (const float*)d_in[17];
    const float* w_hh      = (const float*)d_in[18];
    const float* b_ih      = (const float*)d_in[19];
    const float* b_hh      = (const float*)d_in[20];
    const float* out1_w    = (const float*)d_in[21];
    const float* out1_b    = (const float*)d_in[22];
    const float* out2_w    = (const float*)d_in[23];
    const float* out2_b    = (const float*)d_in[24];
    float* out = (float*)d_out;

    // ---- byte arena ----
    char* base = (char*)d_ws;
    u16* wb = (u16*)base;                         // bf16 weight arena (contiguous)
    u16* fc_wb   = wb;
    u16* inp_wb  = wb + 524288;
    u16* outp_wb = wb + 3670016;
    u16* ff1_wb  = wb + 4718592;
    u16* ff2_wb  = wb + 6815744;
    u16* wih_b   = wb + 8912896;
    u16* whh_b   = wb + 13107200;
    u16* out1_wb = wb + 17301504;
    char* A1 = base + 35651584;   // 21.0 MB: qkv_b | tmp1+tmp2 f32 | gx_b | o1
    char* S1 = A1 + 20971520;     // 10.5 MB: x_b | ff1_b
    char* S2 = S1 + 10485760;     //  5.2 MB: ctx_b | ln1_b | enc_b
    u16*  hb = (u16*)(S2 + 5242880);              // h bf16 [M,H]
    float* buf0 = (float*)((char*)hb + 5242880);  // h f32 [M,H]
    float* cstate = (float*)((char*)buf0 + 10485760);
    u16*  hs0 = (u16*)((char*)cstate + 1048576);  // LSTM h ping
    u16*  hs1 = (u16*)((char*)hs0 + 524288);      // LSTM h pong
    float* bsum = (float*)((char*)hs1 + 524288);

    u16*   qkv_b = (u16*)A1;
    float* tmp1  = (float*)A1;
    float* tmp2  = (float*)(A1 + 10485760);
    u16*   gx_b  = (u16*)A1;
    float* o1    = (float*)A1;
    u16*   x_b   = (u16*)S1;
    u16*   ff1b  = (u16*)S1;
    u16*   ctx_b = (u16*)S2;
    u16*   ln1b  = (u16*)S2;
    u16*   enc_b = (u16*)S2;

    float* gv_out = out + (size_t)M_ * 2;            // cT [B,NL,H]
    float* uv_out = gv_out + (size_t)B_ * NL * H_;   // hT [B,NL,H]

    hipLaunchKernelGGL(bias_sum, dim3(4 * H_ / 256), dim3(256), 0, stream, b_ih, b_hh, bsum);
    hipLaunchKernelGGL(cvt_f2b, dim3(M_ * D_ / 256), dim3(256), 0, stream, x, x_b, M_ * D_);
    hipLaunchKernelGGL(cvt_weights, dim3(17825792 / 256), dim3(256), 0, stream,
                       fc_w, in_proj_w, out_proj_w, ff1_w, ff2_w, w_ih, w_hh, out1_w, wb);

    // fc: h = relu(x @ fc_w^T + fc_b) -> f32 + bf16   [2560,512]x[1024,512]^T
    hipLaunchKernelGGL((gemm_mfma<64, 128, true, true, true>),
                       dim3(H_ / 128, M_ / 64), dim3(256), 0, stream,
                       x_b, fc_wb, fc_b, buf0, hb, M_, H_, D_);

    for (int layer = 0; layer < NL; ++layer) {
        // qkv (bf16 only)
        hipLaunchKernelGGL((gemm_mfma<128, 128, false, false, true>),
                           dim3(3 * H_ / 128, M_ / 128), dim3(256), 0, stream,
                           hb, inp_wb, in_proj_b, (float*)nullptr, qkv_b, M_, 3 * H_, H_);
        hipLaunchKernelGGL(attn_kernel, dim3(B_ * NHEAD), dim3(256), 0, stream, qkv_b, ctx_b);
        // attn out-proj (f32 only)
        hipLaunchKernelGGL((gemm_mfma<64, 128, false, true, false>),
                           dim3(H_ / 128, M_ / 64), dim3(256), 0, stream,
                           ctx_b, outp_wb, out_proj_b, tmp1, (u16*)nullptr, M_, H_, H_);
        hipLaunchKernelGGL(ln_kernel, dim3(M_), dim3(256), 0, stream,
                           buf0, tmp1, ln1_w, ln1_b, tmp2, ln1b);
        // ff1 relu (bf16 only)
        hipLaunchKernelGGL((gemm_mfma<128, 128, true, false, true>),
                           dim3(FF_ / 128, M_ / 128), dim3(256), 0, stream,
                           ln1b, ff1_wb, ff1_b, (float*)nullptr, ff1b, M_, FF_, H_);
        // ff2 (f32 only)
        hipLaunchKernelGGL((gemm_mfma<64, 128, false, true, false>),
                           dim3(H_ / 128, M_ / 64), dim3(256), 0, stream,
                           ff1b, ff2_wb, ff2_b, tmp1, (u16*)nullptr, M_, H_, FF_);
        hipLaunchKernelGGL(ln_kernel, dim3(M_), dim3(256), 0, stream,
                           tmp2, tmp1, ln2_w, ln2_b, (float*)nullptr, enc_b);
        // LSTM input gates for all t (bf16 only, both biases folded in)
        hipLaunchKernelGGL((gemm_mfma<128, 128, false, false, true>),
                           dim3(4 * H_ / 128, M_ / 128), dim3(256), 0, stream,
                           enc_b, wih_b, bsum, (float*)nullptr, gx_b, M_, 4 * H_, H_);
        hipLaunchKernelGGL(init_states, dim3(B_ * H_ / 256), dim3(256), 0, stream,
                           user_vec, game_vec, layer, hs0, cstate);
        for (int t = 0; t < T_; ++t) {
            const bool last = (t == T_ - 1);
            hipLaunchKernelGGL(lstm_step, dim3(32, 4), dim3(256), 0, stream,
                               (t & 1) ? hs1 : hs0, whh_b, gx_b, cstate,
                               (t & 1) ? hs0 : hs1, buf0, hb, t,
                               last ? (uv_out + layer * H_) : nullptr,
                               last ? (gv_out + layer * H_) : nullptr);
        }
    }

    // head: o1 = relu(lstm_out @ out1_w^T + out1_b), then 2-class log_softmax
    hipLaunchKernelGGL((gemm_mfma<64, 64, true, true, false>),
                       dim3((H_ / 2) / 64, M_ / 64), dim3(256), 0, stream,
                       hb, out1_wb, out1_b, o1, (u16*)nullptr, M_, H_ / 2, H_);
    hipLaunchKernelGGL(head_kernel, dim3(M_ / 4), dim3(256), 0, stream, o1, out2_w, out2_b, out);
}